// Round 14
// baseline (397.235 us; speedup 1.0000x reference)
//
#include <hip/hip_runtime.h>
#include <hip/hip_bf16.h>
#include <stdint.h>

// NeighborAttention, MI355X gfx950 — round 14: r13 with __launch_bounds__(256,2).
// r13 counters: VGPR_Count=76 — the compiler squeezed registers for an
// occupancy tier that LDS (49.6KB -> 3 blocks/CU) makes unreachable, forcing
// serial issue/wait/reuse of LDS reads and MFMA operands. Per-node-iteration
// wall = ~18K cycles vs ~1.2K computed chain. min-waves 3 -> 2 raises the
// register budget (expect ~120-180 VGPR); LDS still caps residency at 3
// blocks, so occupancy is unchanged while ILP is restored. No other change.
// B=4,N=4096,K=32,C=128,H=4,d=32. 16 nodes/block, 256 thr, grid 1024.

typedef __attribute__((ext_vector_type(8))) short short8;   // 8 bf16 = 16 B
typedef __attribute__((ext_vector_type(4))) float f32x4;

#define NPB   16
#define CDIM  128
#define KN    32
#define ESTR  136   // LDS row stride (bf16 units)
#define CATS  392   // sCat row stride (bf16 units)
#define NEGI  -3.0e38f

__device__ __forceinline__ float bf2f(short s) {
    union { unsigned int u; float f; } v;
    v.u = ((unsigned int)(unsigned short)s) << 16;
    return v.f;
}
__device__ __forceinline__ short f2bf(float f) {   // RNE scalar
    union { float ff; unsigned int u; } v; v.ff = f;
    unsigned int u = v.u;
    u += 0x7FFFu + ((u >> 16) & 1u);
    return (short)(u >> 16);
}

// 8 x fp32 -> 8 x bf16 via packed cvt (v_cvt_pk_bf16_f32), RNE
__device__ __forceinline__ short8 cvt8(const f32x4& a, const f32x4& b) {
    union { __hip_bfloat162 h; unsigned int u; } c0, c1, c2, c3;
    c0.h = __float22bfloat162_rn(float2{a[0], a[1]});
    c1.h = __float22bfloat162_rn(float2{a[2], a[3]});
    c2.h = __float22bfloat162_rn(float2{b[0], b[1]});
    c3.h = __float22bfloat162_rn(float2{b[2], b[3]});
    short8 r;
    r[0] = (short)(c0.u & 0xffff); r[1] = (short)(c0.u >> 16);
    r[2] = (short)(c1.u & 0xffff); r[3] = (short)(c1.u >> 16);
    r[4] = (short)(c2.u & 0xffff); r[5] = (short)(c2.u >> 16);
    r[6] = (short)(c3.u & 0xffff); r[7] = (short)(c3.u >> 16);
    return r;
}

template<bool FP32>
__device__ __forceinline__ short8 load8bf(const void* p, size_t idx) {
    if constexpr (FP32) {
        const float* fp = (const float*)p + idx;
        f32x4 a = *(const f32x4*)fp;
        f32x4 b = *(const f32x4*)(fp + 4);
        return cvt8(a, b);
    } else {
        return *(const short8*)((const short*)p + idx);
    }
}

template<bool FP32>
__device__ __forceinline__ short loadbf1(const void* p, size_t idx) {
    if constexpr (FP32) return f2bf(((const float*)p)[idx]);
    else return ((const short*)p)[idx];
}

// in-kernel dtype detect: fp32 low half-words decode to wild/NaN bf16s
__device__ __forceinline__ bool detect_fp32(const short* wp) {
    const int lane = threadIdx.x & 63;
    int cnt = 0;
    #pragma unroll
    for (int i = 0; i < 8; ++i) {
        const float v = bf2f(wp[lane + i * 64]);
        if (!(fabsf(v) < 8.0f)) cnt++;
    }
    #pragma unroll
    for (int d = 1; d < 64; d <<= 1) cnt += __shfl_xor(cnt, d);
    return cnt > 16;
}

struct alignas(16) Smem {
    short sEb[2][32 * ESTR];   // 17408 B  double-buffered 32-row node tiles
    short sT[64 * ESTR];       // 17408 B  t = (q·Wk)*scale (bf16), row=(n,h)
    union {
        short sQ[16 * ESTR];   //  4352 B  q rows (prologue only)
        short sCat[16 * CATS]; // 12544 B  [mean|sum|max] (main loop + epilogue)
    } u;
    int      sMask[NPB * KN];  //  2048 B  raw mask (prologue / ballot source)
    unsigned sMaskBits[NPB];   //    64 B  bit k = (mask[node][k] > 0)
};                             // 49472 B -> 3 blocks/CU

// issue loads for one 32x128 node tile (16 KB fp32 / 8 KB bf16), 64 B/thread
template<bool FP32>
__device__ __forceinline__ void issueN(const void* hE, size_t base, int tid,
                                       f32x4 (&pF)[2][2], short8 (&pB)[2]) {
    if constexpr (FP32) {
        #pragma unroll
        for (int it = 0; it < 2; ++it) {
            const float* p = (const float*)hE + base + (size_t)(it * 256 + tid) * 8;
            pF[it][0] = *(const f32x4*)p;
            pF[it][1] = *(const f32x4*)(p + 4);
        }
    } else {
        #pragma unroll
        for (int it = 0; it < 2; ++it)
            pB[it] = *(const short8*)((const short*)hE + base + (size_t)(it * 256 + tid) * 8);
    }
    __builtin_amdgcn_sched_barrier(0);   // pin issue position (r4-proven)
}

template<bool FP32>
__device__ __forceinline__ void writeN(short* dst, int tid,
                                       const f32x4 (&pF)[2][2], const short8 (&pB)[2]) {
    #pragma unroll
    for (int it = 0; it < 2; ++it) {
        const int chunk = it * 256 + tid, row = chunk >> 4, cc = chunk & 15;
        short8 v;
        if constexpr (FP32) v = cvt8(pF[it][0], pF[it][1]);
        else                v = pB[it];
        *(short8*)&dst[row * ESTR + cc * 8] = v;
    }
}

template<bool FP32>
__device__ __forceinline__ void na_body(Smem& sm,
    const void* __restrict__ hX, const void* __restrict__ hE,
    const int* __restrict__ mask, const void* __restrict__ WQ,
    const void* __restrict__ WK, const void* __restrict__ WV,
    const void* __restrict__ WO, void* __restrict__ out)
{
    const int tid  = threadIdx.x;
    const int lane = tid & 63;
    const int w    = tid >> 6;      // wave 0..3 == head owner
    const int quad = lane >> 4;
    const int l15  = lane & 15;
    const int nb   = blockIdx.x * NPB;
    const size_t ebase = (size_t)nb * (KN * CDIM);

    // ---- issue E(node 0) prefetch first ----
    f32x4 pF[2][2]; short8 pB[2];
    issueN<FP32>(hE, ebase, tid, pF, pB);

    // ---- stage mask (coalesced, 2 ints/thread) ----
    *(int2*)&sm.sMask[tid * 2] = *(const int2*)&mask[(size_t)nb * KN + tid * 2];

    // ---- X A-frags + WQ B-frags; q = X @ WQ^T -> u.sQ ----
    short8 ax[4];
    #pragma unroll
    for (int kk = 0; kk < 4; ++kk)
        ax[kk] = load8bf<FP32>(hX, (size_t)(nb + l15) * CDIM + kk * 32 + quad * 8);
    short8 bq[2][4];
    #pragma unroll
    for (int t2 = 0; t2 < 2; ++t2)
        #pragma unroll
        for (int kk = 0; kk < 4; ++kk)
            bq[t2][kk] = load8bf<FP32>(WQ, (size_t)(w * 32 + t2 * 16 + l15) * CDIM + kk * 32 + quad * 8);
    {
        f32x4 o0 = {0.f,0.f,0.f,0.f}, o1 = {0.f,0.f,0.f,0.f};
        #pragma unroll
        for (int kk = 0; kk < 4; ++kk) {
            o0 = __builtin_amdgcn_mfma_f32_16x16x32_bf16(ax[kk], bq[0][kk], o0, 0, 0, 0);
            o1 = __builtin_amdgcn_mfma_f32_16x16x32_bf16(ax[kk], bq[1][kk], o1, 0, 0, 0);
        }
        #pragma unroll
        for (int r = 0; r < 4; ++r) {
            const int n = quad * 4 + r;
            sm.u.sQ[n * ESTR + w * 32 + l15]      = f2bf(o0[r]);
            sm.u.sQ[n * ESTR + w * 32 + 16 + l15] = f2bf(o1[r]);
        }
    }
    __syncthreads();   // B1: sQ + sMask ready

    // ---- per-node mask bitmasks: wave w ballots nodes 4w..4w+3 ----
    #pragma unroll
    for (int t = 0; t < 4; ++t) {
        const int n = w * 4 + t;
        const bool bit = (lane < 32) && (sm.sMask[n * KN + (lane & 31)] > 0);
        const unsigned long long bal = __ballot(bit);
        if (lane == 0) sm.sMaskBits[n] = (unsigned)bal;
    }

    // ---- WK B-frags (gather) ; t = (q·WK)*scale -> sT (row=(n,h)) ----
    short8 bk[2][4];
    #pragma unroll
    for (int t2 = 0; t2 < 2; ++t2)
        #pragma unroll
        for (int kk = 0; kk < 4; ++kk) {
            const int j = w * 32 + t2 * 16 + l15;
            short8 b;
            #pragma unroll
            for (int jj = 0; jj < 8; ++jj)
                b[jj] = loadbf1<FP32>(WK, (size_t)(kk * 32 + quad * 8 + jj) * CDIM + j);
            bk[t2][kk] = b;
        }
    {
        const float scale = 0.17677669529663687f;   // 1/sqrt(32)
        const short8 zz = {0,0,0,0,0,0,0,0};
        #pragma unroll
        for (int m = 0; m < 4; ++m) {
            const int n_g = m * 4 + (l15 >> 2), h_ = l15 & 3;
            const short8 qv = *(const short8*)&sm.u.sQ[n_g * ESTR + h_ * 32 + quad * 8];
            f32x4 c0 = {0.f,0.f,0.f,0.f}, c1 = {0.f,0.f,0.f,0.f};
            #pragma unroll
            for (int kk = 0; kk < 4; ++kk) {
                const short8 af = (kk == h_) ? qv : zz;
                c0 = __builtin_amdgcn_mfma_f32_16x16x32_bf16(af, bk[0][kk], c0, 0, 0, 0);
                c1 = __builtin_amdgcn_mfma_f32_16x16x32_bf16(af, bk[1][kk], c1, 0, 0, 0);
            }
            #pragma unroll
            for (int r = 0; r < 4; ++r) {
                const int row = m * 16 + quad * 4 + r;        // (n,h) row
                sm.sT[row * ESTR + w * 32 + l15]      = f2bf(c0[r] * scale);
                sm.sT[row * ESTR + w * 32 + 16 + l15] = f2bf(c1[r] * scale);
            }
        }
    }

    // ---- WV B-frags (block lifetime, wave w owns channel cols 32w..+31) ----
    short8 bv[2][4];
    #pragma unroll
    for (int ct2 = 0; ct2 < 2; ++ct2)
        #pragma unroll
        for (int kk = 0; kk < 4; ++kk)
            bv[ct2][kk] = load8bf<FP32>(WV, (size_t)((2 * w + ct2) * 16 + l15) * CDIM + kk * 32 + quad * 8);

    // ---- stage node 0, issue node 1 ----
    writeN<FP32>(sm.sEb[0], tid, pF, pB);
    issueN<FP32>(hE, ebase + 1 * (KN * CDIM), tid, pF, pB);
    __syncthreads();   // B2: sT + sEb[0] + sMaskBits ready; pf = E(1) in flight

    // ================= node loop: 1 NON-DRAINING barrier per node ============
    #pragma unroll 1
    for (int i = 0; i < NPB; ++i) {
        const short* bufp = sm.sEb[i & 1];

        // ---- frags: A = node rows; B = t row (i*4 + w) -> HEAD w broadcast ----
        short8 a0[4], a1[4], bs[4];
        #pragma unroll
        for (int kk = 0; kk < 4; ++kk) {
            bs[kk] = *(const short8*)&sm.sT[(i * 4 + w) * ESTR + kk * 32 + quad * 8];
            a0[kk] = *(const short8*)&bufp[l15 * ESTR + kk * 32 + quad * 8];
            a1[kk] = *(const short8*)&bufp[(16 + l15) * ESTR + kk * 32 + quad * 8];
        }

        // ---- scores for head w: every col identical; row -> k ----
        f32x4 s0 = {0.f,0.f,0.f,0.f}, s1 = {0.f,0.f,0.f,0.f};
        #pragma unroll
        for (int kk = 0; kk < 4; ++kk) {
            s0 = __builtin_amdgcn_mfma_f32_16x16x32_bf16(a0[kk], bs[kk], s0, 0, 0, 0);
            s1 = __builtin_amdgcn_mfma_f32_16x16x32_bf16(a1[kk], bs[kk], s1, 0, 0, 0);
        }

        // ---- masked softmax (head w) fully in-register; bitmask masks ----
        float x[8], ainv;
        {
            const unsigned mb = sm.sMaskBits[i];   // broadcast ds_read_b32
            float m = NEGI;
            #pragma unroll
            for (int j = 0; j < 4; ++j) {
                x[j]     = s0[j];
                x[4 + j] = s1[j];
                m = fmaxf(m, ((mb >> (quad * 4 + j)) & 1u)      ? s0[j] : NEGI);
                m = fmaxf(m, ((mb >> (16 + quad * 4 + j)) & 1u) ? s1[j] : NEGI);
            }
            m = fmaxf(m, __shfl_xor(m, 16));
            m = fmaxf(m, __shfl_xor(m, 32));
            float dsum = 0.f;
            #pragma unroll
            for (int j = 0; j < 4; ++j) {
                const float e0 = __expf(fminf(x[j] - m, 0.f))
                                 * (((mb >> (quad * 4 + j)) & 1u) ? 1.f : 0.f);
                const float e1 = __expf(fminf(x[4 + j] - m, 0.f))
                                 * (((mb >> (16 + quad * 4 + j)) & 1u) ? 1.f : 0.f);
                x[j] = e0; x[4 + j] = e1;
                dsum += e0 + e1;
            }
            dsum += __shfl_xor(dsum, 16);
            dsum += __shfl_xor(dsum, 32);
            const float inv = (dsum > 0.f) ? (1.f / dsum) : 0.f;
            #pragma unroll
            for (int j = 0; j < 8; ++j) x[j] *= inv;
            ainv = 1.0f / (((dsum > 0.f) ? 1.0f : 0.0f) + 1e-8f);
        }

        // ---- stage next node into the other buffer; issue node i+2 ----
        if (i < NPB - 1) {
            writeN<FP32>(sm.sEb[(i + 1) & 1], tid, pF, pB);   // pf = E(i+1)
            if (i < NPB - 2)
                issueN<FP32>(hE, ebase + (size_t)(i + 2) * (KN * CDIM), tid, pF, pB);
        }

        // ---- PV + aggregation: lane already holds head-w attn (no shuffles) --
        #pragma unroll
        for (int ct2 = 0; ct2 < 2; ++ct2) {
            f32x4 av0 = {0.f,0.f,0.f,0.f}, av1 = {0.f,0.f,0.f,0.f};
            #pragma unroll
            for (int kk = 0; kk < 4; ++kk) {
                av0 = __builtin_amdgcn_mfma_f32_16x16x32_bf16(a0[kk], bv[ct2][kk], av0, 0, 0, 0);
                av1 = __builtin_amdgcn_mfma_f32_16x16x32_bf16(a1[kk], bv[ct2][kk], av1, 0, 0, 0);
            }
            float sum = 0.f, mx = NEGI;
            #pragma unroll
            for (int r = 0; r < 4; ++r) {
                const float p0 = x[r]     * av0[r];
                const float p1 = x[4 + r] * av1[r];
                sum += p0 + p1;
                mx = fmaxf(mx, fmaxf(p0, p1));
            }
            sum += __shfl_xor(sum, 16);
            sum += __shfl_xor(sum, 32);
            mx = fmaxf(mx, __shfl_xor(mx, 16));
            mx = fmaxf(mx, __shfl_xor(mx, 32));
            if (quad == 0) {
                const int c = (2 * w + ct2) * 16 + l15;
                sm.u.sCat[i * CATS + c]       = f2bf(sum * ainv);  // mean
                sm.u.sCat[i * CATS + 128 + c] = f2bf(sum);         // sum
                sm.u.sCat[i * CATS + 256 + c] = f2bf(mx);          // max
            }
        }

        // ---- NON-DRAINING barrier (r10): lgkmcnt only, no vmcnt drain ----
        asm volatile("s_waitcnt lgkmcnt(0)" ::: "memory");
        __builtin_amdgcn_s_barrier();
        __builtin_amdgcn_sched_barrier(0);
    }
    __syncthreads();   // full drain before epilogue reads sCat

    // ---- P7: out = cat @ WO^T via MFMA (M=16, K=384, wave owns 32 cols) ----
    {
        f32x4 o0 = {0.f,0.f,0.f,0.f}, o1 = {0.f,0.f,0.f,0.f};
        #pragma unroll
        for (int kk = 0; kk < 12; ++kk) {
            const short8 a  = *(const short8*)&sm.u.sCat[l15 * CATS + kk * 32 + quad * 8];
            const short8 b0 = load8bf<FP32>(WO, (size_t)(w * 32 + l15) * 384 + kk * 32 + quad * 8);
            const short8 b1 = load8bf<FP32>(WO, (size_t)(w * 32 + 16 + l15) * 384 + kk * 32 + quad * 8);
            o0 = __builtin_amdgcn_mfma_f32_16x16x32_bf16(a, b0, o0, 0, 0, 0);
            o1 = __builtin_amdgcn_mfma_f32_16x16x32_bf16(a, b1, o1, 0, 0, 0);
        }
        #pragma unroll
        for (int r = 0; r < 4; ++r) {
            const int node = quad * 4 + r;
            const size_t base = (size_t)(nb + node) * CDIM + w * 32;
            if constexpr (FP32) {
                ((float*)out)[base + l15]      = o0[r];
                ((float*)out)[base + 16 + l15] = o1[r];
            } else {
                ((short*)out)[base + l15]      = f2bf(o0[r]);
                ((short*)out)[base + 16 + l15] = f2bf(o1[r]);
            }
        }
    }
}

__global__ __launch_bounds__(256, 2)
void na_fused(const void* __restrict__ hX, const void* __restrict__ hE,
              const int* __restrict__ mask, const void* __restrict__ WQ,
              const void* __restrict__ WK, const void* __restrict__ WV,
              const void* __restrict__ WO, void* __restrict__ out)
{
    __shared__ Smem sm;
    if (detect_fp32((const short*)WQ)) na_body<true >(sm, hX, hE, mask, WQ, WK, WV, WO, out);
    else                               na_body<false>(sm, hX, hE, mask, WQ, WK, WV, WO, out);
}

extern "C" void kernel_launch(void* const* d_in, const int* in_sizes, int n_in,
                              void* d_out, int out_size, void* d_ws, size_t ws_size,
                              hipStream_t stream) {
    (void)in_sizes; (void)n_in; (void)ws_size; (void)out_size; (void)d_ws;
    const void* hX   = d_in[0];
    const void* hE   = d_in[1];
    const int*  mask = (const int*)d_in[2];
    const void* WQ   = d_in[3];
    const void* WK   = d_in[4];
    const void* WV   = d_in[5];
    const void* WO   = d_in[6];

    na_fused<<<dim3(1024), dim3(256), 0, stream>>>(hX, hE, mask, WQ, WK, WV, WO, d_out);
}